// Round 17
// baseline (256.629 us; speedup 1.0000x reference)
//
#include <hip/hip_runtime.h>
#include <hip/hip_bf16.h>

#define BLOCK 512
#define IPB 8            // images per block (conv kernel)
#define EIPB 16          // images per block (expert kernel)
#define FB_STRIDE 1616   // fused-path featbuf stride (shorts)
#define ES_STRIDE 1608   // expert featS stride: 804 dw = 4 mod 32 -> 16-row reads ~2-way
#define H1_STRIDE 40     // h1p row stride in shorts: 80 B, 16B-aligned

// ws layout (shorts):
#define W2T_OFF 0        // [kpos=9][oc=64][j=32]  (j = ic-pair-interleaved)   18432
#define EWT_OFF 18432    // [ks=50][n=64][k=32] experts+gate (k perm'd)        102400
#define W1C_OFF 120832   // [n=32][k=32] conv1 B: k0-8 w1hi, k16-24 w1lo, rest 0
#define WS_SHORTS 121856
#define FEAT_OFF 121856  // [B][1600] bf16 feat (k perm'd) — full path only

typedef __attribute__((ext_vector_type(8))) short short8;
typedef __attribute__((ext_vector_type(4))) float f32x4;

#define SEL_LO 0x05040100u   // perm(y,x,SEL_LO) = (x&0xffff)|(y<<16) : low halves

static __device__ __forceinline__ unsigned short f2bf(float f) {
    unsigned int u = __builtin_bit_cast(unsigned int, f);
    u = (u + 0x7FFFu + ((u >> 16) & 1u)) >> 16;   // RNE
    return (unsigned short)u;
}
static __device__ __forceinline__ float bf2f(unsigned short h) {
    unsigned int u = ((unsigned int)h) << 16;
    return __builtin_bit_cast(float, u);
}
// single-instruction RNE pack: low16 = bf16(a), high16 = bf16(b)
static __device__ __forceinline__ unsigned int cvtpk(float a, float b) {
    unsigned int r;
    asm("v_cvt_pk_bf16_f32 %0, %1, %2" : "=v"(r) : "v"(a), "v"(b));
    return r;
}

// ---------------- prep kernel: build bf16 weight layouts in d_ws ----------------
__global__ void moe_prep(const float* __restrict__ w2, const float* __restrict__ gw,
                         const float* __restrict__ ew, const float* __restrict__ w1,
                         unsigned short* __restrict__ ws) {
    int i = blockIdx.x * 256 + threadIdx.x;
    if (i < 18432) {
        int kpos = i >> 11, rem = i & 2047, oc = rem >> 5, j = rem & 31;
        int ic = ((j & 1) << 4) | (j >> 1);        // h1p pair-interleave: j=2*l+h <-> ic=h*16+l
        ws[W2T_OFF + i] = f2bf(w2[(kpos * 32 + ic) * 64 + oc]);
    }
    int j2 = i - EWT_OFF;
    if (j2 >= 0 && j2 < 102400) {
        int ks = j2 >> 11, rem = j2 & 2047, n = rem >> 5, k = rem & 31;
        int kk = ks * 32 + k;                      // permuted flatten index
        int wv = kk >> 6, jj = kk & 63;
        int r = jj & 31;
        int oc = ((jj >> 5) << 5) | ((r & 1) << 4) | (r >> 1);   // feat pair-interleave
        int d = wv * 64 + oc;                      // original flatten dim
        float v = 0.f;
        if (n < 50)      v = ew[(n / 10) * 16000 + d * 10 + (n % 10)];
        else if (n < 55) v = gw[d * 5 + (n - 50)];
        ws[EWT_OFF + j2] = f2bf(v);
    }
    int p = i - W1C_OFF;
    if (p >= 0 && p < 1024) {
        // conv1 B, two-pattern layout: k0-8 = w1hi(tap k), k16-24 = w1lo(tap k-16), rest 0
        int n = p >> 5, k = p & 31;
        unsigned short val = 0;
        if (k < 9) {
            val = f2bf(w1[k * 32 + n]);
        } else if (k >= 16 && k < 25) {
            float w = w1[(k - 16) * 32 + n];
            unsigned short hi = f2bf(w);
            val = f2bf(w - bf2f(hi));
        }
        ws[W1C_OFF + p] = val;
    }
}

// ---------------- conv kernel: conv1+pool -> conv2+pool -> feat (global) ----------------
// NOTE: this toolchain treats __launch_bounds__ arg2 as min BLOCKS/CU (CUDA semantics).
// N=4 pins the 64-VGPR HW bucket (waves/CU halve past 64 VGPR — round-15 lesson).
// conv2: wave owns 1 M-tile (mt=wid) x ALL 4 N-tiles -> each afrag LDS read feeds 4 MFMAs
// (halves LDS-pipe traffic vs 2x2; bfrag re-loads ride L1/L2, compiler reloads them anyway).
__global__ __launch_bounds__(BLOCK, 4)
void moe_conv(const float* __restrict__ x, const float* __restrict__ b1,
              const float* __restrict__ b2, const unsigned short* __restrict__ ws,
              unsigned short* __restrict__ feat, int B)
{
    __shared__ unsigned int xsp[2][784];                        // bf16(x) dup-packed, 6272 B
    __shared__ __align__(16) unsigned short h1p[2][169 * H1_STRIDE];   // 27040 B

    const int tid  = threadIdx.x;
    const int wid  = tid >> 6;
    const int lane = tid & 63;
    const int l15  = lane & 15;
    const int lg   = lane >> 4;

    const short8 c1f0 = *(const short8*)&ws[W1C_OFF + l15 * 32 + lg * 8];
    const short8 c1f1 = *(const short8*)&ws[W1C_OFF + (16 + l15) * 32 + lg * 8];

    // per-lane bias constants (L1/L2 hits)
    const float bias1a = b1[l15];
    const float bias1b = b1[16 + l15];
    const float bias2v0 = b2[l15];
    const float bias2v1 = b2[16 + l15];
    const float bias2v2 = b2[32 + l15];
    const float bias2v3 = b2[48 + l15];

    // ---- image-invariant conv1 addressing (hoisted out of image loop) ----
    int xoff1[6], hoff1[6];
    bool val1[6];
    #pragma unroll
    for (int j = 0; j < 6; ++j) {
        const int mt = wid + 8 * j;
        int wsrc = mt * 4 + (l15 >> 2); if (wsrc > 168) wsrc = 168;
        const int s = l15 & 3;
        const int cy = 2 * (wsrc / 13) + (s >> 1);
        const int cx = 2 * (wsrc % 13) + (s & 1);
        xoff1[j] = cy * 28 + cx;
        const int window = mt * 4 + lg;
        val1[j] = (mt < 43) && (window < 169);
        hoff1[j] = (window < 169 ? window : 0) * H1_STRIDE + 2 * l15;
    }
    // ---- image-invariant conv2 addressing: wave owns mt = wid ----
    int aoff2, foff2;
    bool val2;
    {
        const int mt = wid;
        const int m = mt * 16 + l15;
        int wsrc = m >> 2; if (wsrc > 24) wsrc = 24;
        const int s = m & 3;
        const int cy = 2 * (wsrc / 5) + (s >> 1);
        const int cx = 2 * (wsrc % 5) + (s & 1);
        aoff2 = (cy * 13 + cx) * (H1_STRIDE * 2) + lg * 16;   // byte offset into h1p
        const int wv = mt * 4 + lg;
        val2 = (wv < 25);
        foff2 = (wv < 25 ? wv : 0) * 64 + 2 * l15;
    }
    // per-lane bfrag global bases (kp-invariant parts)
    const unsigned short* bf0 = ws + W2T_OFF + (0 * 16 + l15) * 32 + lg * 8;
    const unsigned short* bf1 = ws + W2T_OFF + (1 * 16 + l15) * 32 + lg * 8;
    const unsigned short* bf2p = ws + W2T_OFF + (2 * 16 + l15) * 32 + lg * 8;
    const unsigned short* bf3 = ws + W2T_OFF + (3 * 16 + l15) * 32 + lg * 8;

    const int img0 = blockIdx.x * IPB;
    {   // prologue: stage image 0 (bf16 dup-packed, 1 cvt_pk per element)
        int im = img0 < B ? img0 : B - 1;
        const float* xg = x + (size_t)im * 784;
        xsp[0][tid] = cvtpk(xg[tid], xg[tid]);
        if (tid + BLOCK < 784) xsp[0][tid + BLOCK] = cvtpk(xg[tid + BLOCK], xg[tid + BLOCK]);
    }
    __syncthreads();

    // software-pipelined phases: phase p = conv2(img p-1) || conv1(img p)
    #pragma unroll
    for (int p = 0; p <= IPB; ++p) {
        const bool do_c1 = (p < IPB);
        const bool do_c2 = (p >= 1);
        const bool pre   = (p + 1 < IPB);

        float f0 = 0.f, f1 = 0.f;
        if (pre) {
            int im2 = img0 + p + 1; if (im2 >= B) im2 = B - 1;
            const float* xg2 = x + (size_t)im2 * 784;
            f0 = xg2[tid];
            if (tid + BLOCK < 784) f1 = xg2[tid + BLOCK];
        }

        // conv2(img p-1): 1 mt x 4 nt per wave; one afrag read feeds 4 MFMAs
        if (do_c2) {
            const int it = p - 1;
            const int img = img0 + it;
            const unsigned short* h1cur = h1p[it & 1];
            unsigned short* frow = feat + (size_t)img * 1600;
            const char* abase = (const char*)h1cur + aoff2;
            f32x4 a0 = {0.f, 0.f, 0.f, 0.f};
            f32x4 a1 = {0.f, 0.f, 0.f, 0.f};
            f32x4 a2 = {0.f, 0.f, 0.f, 0.f};
            f32x4 a3 = {0.f, 0.f, 0.f, 0.f};
            #pragma unroll
            for (int kp = 0; kp < 9; kp++) {
                const int ky = kp / 3, kx = kp % 3;
                const short8 af = *(const short8*)(abase + (ky * 13 + kx) * (H1_STRIDE * 2));
                a0 = __builtin_amdgcn_mfma_f32_16x16x32_bf16(af, *(const short8*)(bf0 + kp * 2048), a0, 0, 0, 0);
                a1 = __builtin_amdgcn_mfma_f32_16x16x32_bf16(af, *(const short8*)(bf1 + kp * 2048), a1, 0, 0, 0);
                a2 = __builtin_amdgcn_mfma_f32_16x16x32_bf16(af, *(const short8*)(bf2p + kp * 2048), a2, 0, 0, 0);
                a3 = __builtin_amdgcn_mfma_f32_16x16x32_bf16(af, *(const short8*)(bf3 + kp * 2048), a3, 0, 0, 0);
            }
            if (val2 && img < B) {
                const float m0 = fmaxf(fmaxf(a0.x, a0.y), fmaxf(a0.z, a0.w)) + bias2v0;
                const float m1 = fmaxf(fmaxf(a1.x, a1.y), fmaxf(a1.z, a1.w)) + bias2v1;
                const float m2 = fmaxf(fmaxf(a2.x, a2.y), fmaxf(a2.z, a2.w)) + bias2v2;
                const float m3 = fmaxf(fmaxf(a3.x, a3.y), fmaxf(a3.z, a3.w)) + bias2v3;
                *(unsigned int*)&frow[foff2]      = cvtpk(fmaxf(m0, 0.f), fmaxf(m1, 0.f));
                *(unsigned int*)&frow[foff2 + 32] = cvtpk(fmaxf(m2, 0.f), fmaxf(m3, 0.f));
            }
        }

        // conv1(img p): branch-sunk tap loads -> MFMA -> h1p
        if (do_c1) {
            const unsigned int* xcur = xsp[p & 1];
            unsigned short* h1dst = h1p[p & 1];
            #pragma unroll
            for (int j = 0; j < 6; ++j) {
                if (wid + 8 * j < 43) {
                    const unsigned int* xb = xcur + xoff1[j];
                    unsigned int a0 = 0u, a1 = 0u, a2 = 0u, a3 = 0u;
                    if ((lg & 1) == 0) {
                        const unsigned int t0 = xb[0],  t1 = xb[1],  t2 = xb[2];
                        const unsigned int t3 = xb[28], t4 = xb[29], t5 = xb[30];
                        const unsigned int t6 = xb[56], t7 = xb[57];
                        a0 = __builtin_amdgcn_perm(t1, t0, SEL_LO);
                        a1 = __builtin_amdgcn_perm(t3, t2, SEL_LO);
                        a2 = __builtin_amdgcn_perm(t5, t4, SEL_LO);
                        a3 = __builtin_amdgcn_perm(t7, t6, SEL_LO);
                    } else {
                        a0 = xb[58] & 0xffffu;
                    }
                    const uint4 av = make_uint4(a0, a1, a2, a3);
                    const short8 af = __builtin_bit_cast(short8, av);
                    f32x4 p0 = {0.f, 0.f, 0.f, 0.f};
                    f32x4 p1 = {0.f, 0.f, 0.f, 0.f};
                    p0 = __builtin_amdgcn_mfma_f32_16x16x32_bf16(af, c1f0, p0, 0, 0, 0);
                    p1 = __builtin_amdgcn_mfma_f32_16x16x32_bf16(af, c1f1, p1, 0, 0, 0);
                    if (val1[j]) {
                        const float m0 = fmaxf(fmaxf(p0.x, p0.y), fmaxf(p0.z, p0.w)) + bias1a;
                        const float m1 = fmaxf(fmaxf(p1.x, p1.y), fmaxf(p1.z, p1.w)) + bias1b;
                        *(unsigned int*)&h1dst[hoff1[j]] = cvtpk(fmaxf(m0, 0.f), fmaxf(m1, 0.f));
                    }
                }
            }
        }

        if (pre) {
            xsp[(p + 1) & 1][tid] = cvtpk(f0, f0);
            if (tid + BLOCK < 784) xsp[(p + 1) & 1][tid + BLOCK] = cvtpk(f1, f1);
        }
        __syncthreads();
    } // p
}

// ---------------- expert kernel: [B x 1600] @ [1600 x 55] + gate/top3/softmax ----------------
// (LDS-staged featS — coalesced global reads, conflict-free MFMA reads)
__global__ __launch_bounds__(BLOCK, 2)
void moe_expert(const unsigned short* __restrict__ ws, const float* __restrict__ gb,
                const float* __restrict__ eb, float* __restrict__ out, int B)
{
    __shared__ __align__(16) unsigned short featS[EIPB * ES_STRIDE];   // 51456 B
    __shared__ float allC[2][EIPB][64];                                 // 8192 B

    const int tid  = threadIdx.x;
    const int wid  = tid >> 6;
    const int lane = tid & 63;
    const int l15  = lane & 15;
    const int lg   = lane >> 4;

    const unsigned short* feat = ws + FEAT_OFF;
    const unsigned short* ewt  = ws + EWT_OFF;
    const int img0 = blockIdx.x * EIPB;

    for (int i = tid; i < EIPB * 800; i += BLOCK) {
        const int r = i / 800, c = i - r * 800;
        const int img = img0 + r;
        unsigned int v = 0u;
        if (img < B) v = *(const unsigned int*)&feat[(size_t)img * 1600 + 2 * c];
        *(unsigned int*)&featS[r * ES_STRIDE + 2 * c] = v;
    }
    __syncthreads();

    {
        const int kh  = wid >> 2;
        const int ntE = wid & 3;
        const int bc  = ntE * 16 + l15;
        f32x4 acc = {0.f, 0.f, 0.f, 0.f};
        const int ks0 = kh * 25;
        for (int ks = ks0; ks < ks0 + 25; ++ks) {
            const short8 af = *(const short8*)&featS[l15 * ES_STRIDE + ks * 32 + lg * 8];
            const short8 bf = *(const short8*)&ewt[(ks * 64 + bc) * 32 + lg * 8];
            acc = __builtin_amdgcn_mfma_f32_16x16x32_bf16(af, bf, acc, 0, 0, 0);
        }
        const int r0 = lg * 4;
        allC[kh][r0 + 0][bc] = acc.x;
        allC[kh][r0 + 1][bc] = acc.y;
        allC[kh][r0 + 2][bc] = acc.z;
        allC[kh][r0 + 3][bc] = acc.w;
    }
    __syncthreads();

    if (tid < EIPB) {
        const int img = img0 + tid;
        if (img < B) {
            float gv[5], mx = -1e30f;
            #pragma unroll
            for (int g = 0; g < 5; g++) {
                gv[g] = allC[0][tid][50 + g] + allC[1][tid][50 + g] + gb[g];
                mx = fmaxf(mx, gv[g]);
            }
            float ssum = 0.f;
            #pragma unroll
            for (int g = 0; g < 5; g++) { gv[g] = expf(gv[g] - mx); ssum += gv[g]; }
            const float inv = 1.f / ssum;
            #pragma unroll
            for (int g = 0; g < 5; g++) gv[g] *= inv;

            int idx0, idx1, idx2; float wv0, wv1, wv2;
            unsigned usedMask = 0;
            {
                int bi = 0; float bv = -1e30f;
                #pragma unroll
                for (int g = 0; g < 5; g++)
                    if (gv[g] > bv) { bv = gv[g]; bi = g; }   // strict >: lowest idx on tie
                idx0 = bi; wv0 = bv; usedMask |= (1u << bi);
            }
            {
                int bi = 0; float bv = -1e30f;
                #pragma unroll
                for (int g = 0; g < 5; g++)
                    if (!(usedMask & (1u << g)) && gv[g] > bv) { bv = gv[g]; bi = g; }
                idx1 = bi; wv1 = bv; usedMask |= (1u << bi);
            }
            {
                int bi = 0; float bv = -1e30f;
                #pragma unroll
                for (int g = 0; g < 5; g++)
                    if (!(usedMask & (1u << g)) && gv[g] > bv) { bv = gv[g]; bi = g; }
                idx2 = bi; wv2 = bv;
            }
            float comb[10];
            #pragma unroll
            for (int cc = 0; cc < 10; cc++) {
                comb[cc] = wv0 * (allC[0][tid][idx0 * 10 + cc] + allC[1][tid][idx0 * 10 + cc] + eb[idx0 * 10 + cc])
                         + wv1 * (allC[0][tid][idx1 * 10 + cc] + allC[1][tid][idx1 * 10 + cc] + eb[idx1 * 10 + cc])
                         + wv2 * (allC[0][tid][idx2 * 10 + cc] + allC[1][tid][idx2 * 10 + cc] + eb[idx2 * 10 + cc]);
            }
            float m2 = -1e30f;
            #pragma unroll
            for (int cc = 0; cc < 10; cc++) m2 = fmaxf(m2, comb[cc]);
            float e[10], s2 = 0.f;
            #pragma unroll
            for (int cc = 0; cc < 10; cc++) { e[cc] = expf(comb[cc] - m2); s2 += e[cc]; }
            const float inv2 = 1.f / s2;
            #pragma unroll
            for (int cc = 0; cc < 10; cc++) out[(size_t)img * 10 + cc] = e[cc] * inv2;
        }
    }
}

// ---------------- fused fallback (used when ws can't hold feat) ----------------
__global__ __launch_bounds__(BLOCK, 3)
void moe_main_fused(const float* __restrict__ x, const float* __restrict__ b1,
                    const float* __restrict__ b2, const float* __restrict__ gb,
                    const float* __restrict__ eb, const unsigned short* __restrict__ ws,
                    float* __restrict__ out, int B)
{
    __shared__ unsigned int xsp[2][784];
    __shared__ __align__(16) unsigned short h1p[2][169 * H1_STRIDE];
    __shared__ __align__(16) unsigned short featbuf[4 * FB_STRIDE];
    __shared__ float allC[2][4 * 56];

    const int tid  = threadIdx.x;
    const int wid  = tid >> 6;
    const int lane = tid & 63;
    const int l15  = lane & 15;
    const int lg   = lane >> 4;

    const int mt0 = wid >> 1;
    const int n0  = (wid & 1) * 2;
    short8 bfA[9], bfB[9];
    #pragma unroll
    for (int kp = 0; kp < 9; kp++) {
        bfA[kp] = *(const short8*)&ws[W2T_OFF + (kp * 64 + n0 * 16 + l15) * 32 + lg * 8];
        bfB[kp] = *(const short8*)&ws[W2T_OFF + (kp * 64 + (n0 + 1) * 16 + l15) * 32 + lg * 8];
    }
    const short8 c1f0 = *(const short8*)&ws[W1C_OFF + l15 * 32 + lg * 8];
    const short8 c1f1 = *(const short8*)&ws[W1C_OFF + (16 + l15) * 32 + lg * 8];

    const float bias1a = b1[l15];
    const float bias1b = b1[16 + l15];
    const float bias2a = b2[n0 * 16 + l15];
    const float bias2b = b2[n0 * 16 + l15 + 16];

    const int img0 = blockIdx.x * 4;
    {
        int im = img0 < B ? img0 : B - 1;
        const float* xg = x + (size_t)im * 784;
        xsp[0][tid] = cvtpk(xg[tid], xg[tid]);
        if (tid + BLOCK < 784) xsp[0][tid + BLOCK] = cvtpk(xg[tid + BLOCK], xg[tid + BLOCK]);
    }
    __syncthreads();

    #pragma unroll
    for (int p = 0; p <= 4; ++p) {
        const bool do_c1 = (p < 4);
        const bool do_c2 = (p >= 1);
        const bool pre   = (p + 1 < 4);

        float f0 = 0.f, f1 = 0.f;
        if (pre) {
            int im2 = img0 + p + 1; if (im2 >= B) im2 = B - 1;
            const float* xg2 = x + (size_t)im2 * 784;
            f0 = xg2[tid];
            if (tid + BLOCK < 784) f1 = xg2[tid + BLOCK];
        }

        if (do_c2) {
            const int it = p - 1;
            const unsigned short* h1cur = h1p[it & 1];
            #pragma unroll
            for (int mi = 0; mi < 2; ++mi) {
                const int mt = mt0 + mi * 4;
                const int m = mt * 16 + l15;
                int wsrc = m >> 2; if (wsrc > 24) wsrc = 24;
                const int s = m & 3;
                const int cy = 2 * (wsrc / 5) + (s >> 1);
                const int cx = 2 * (wsrc % 5) + (s & 1);
                const char* abase = (const char*)h1cur + (cy * 13 + cx) * (H1_STRIDE * 2) + lg * 16;
                f32x4 a0 = {0.f, 0.f, 0.f, 0.f};
                f32x4 a1 = {0.f, 0.f, 0.f, 0.f};
                #pragma unroll
                for (int kp = 0; kp < 9; kp++) {
                    const int ky = kp / 3, kx = kp % 3;
                    const short8 af = *(const short8*)(abase + (ky * 13 + kx) * (H1_STRIDE * 2));
                    a0 = __builtin_amdgcn_mfma_f32_16x16x32_bf16(af, bfA[kp], a0, 0, 0, 0);
                    a1 = __builtin_amdgcn_mfma_f32_16x16x32_bf16(af, bfB[kp], a1, 0, 0, 0);
                }
                const int wv = mt * 4 + lg;
                if (wv < 25) {
                    const float m0 = fmaxf(fmaxf(a0.x, a0.y), fmaxf(a0.z, a0.w)) + bias2a;
                    const float m1 = fmaxf(fmaxf(a1.x, a1.y), fmaxf(a1.z, a1.w)) + bias2b;
                    *(unsigned int*)&featbuf[it * FB_STRIDE + wv * 64 + ((n0 >> 1) << 5) + 2 * l15] =
                        cvtpk(fmaxf(m0, 0.f), fmaxf(m1, 0.f));
                }
            }
        }

        if (do_c1) {
            const unsigned int* xcur = xsp[p & 1];
            unsigned short* h1dst = h1p[p & 1];
            for (int mt = wid; mt < 43; mt += 8) {
                int wsrc = mt * 4 + (l15 >> 2); if (wsrc > 168) wsrc = 168;
                const int s  = l15 & 3;
                const int cy = 2 * (wsrc / 13) + (s >> 1);
                const int cx = 2 * (wsrc % 13) + (s & 1);
                const unsigned int* xb = &xcur[cy * 28 + cx];
                unsigned int a0 = 0u, a1 = 0u, a2 = 0u, a3 = 0u;
                if ((lg & 1) == 0) {
                    const unsigned int t0 = xb[0],  t1 = xb[1],  t2 = xb[2];
                    const unsigned int t3 = xb[28], t4 = xb[29], t5 = xb[30];
                    const unsigned int t6 = xb[56], t7 = xb[57];
                    a0 = __builtin_amdgcn_perm(t1, t0, SEL_LO);
                    a1 = __builtin_amdgcn_perm(t3, t2, SEL_LO);
                    a2 = __builtin_amdgcn_perm(t5, t4, SEL_LO);
                    a3 = __builtin_amdgcn_perm(t7, t6, SEL_LO);
                } else {
                    a0 = xb[58] & 0xffffu;
                }
                const uint4 av = make_uint4(a0, a1, a2, a3);
                const short8 af = __builtin_bit_cast(short8, av);
                f32x4 p0 = {0.f, 0.f, 0.f, 0.f};
                f32x4 p1 = {0.f, 0.f, 0.f, 0.f};
                p0 = __builtin_amdgcn_mfma_f32_16x16x32_bf16(af, c1f0, p0, 0, 0, 0);
                p1 = __builtin_amdgcn_mfma_f32_16x16x32_bf16(af, c1f1, p1, 0, 0, 0);
                const int window = mt * 4 + lg;
                if (window < 169) {
                    const float m0 = fmaxf(fmaxf(p0.x, p0.y), fmaxf(p0.z, p0.w)) + bias1a;
                    const float m1 = fmaxf(fmaxf(p1.x, p1.y), fmaxf(p1.z, p1.w)) + bias1b;
                    *(unsigned int*)&h1dst[window * H1_STRIDE + 2 * l15] =
                        cvtpk(fmaxf(m0, 0.f), fmaxf(m1, 0.f));
                }
            }
        }

        if (pre) {
            xsp[(p + 1) & 1][tid] = cvtpk(f0, f0);
            if (tid + BLOCK < 784) xsp[(p + 1) & 1][tid + BLOCK] = cvtpk(f1, f1);
        }
        __syncthreads();
    } // p

    {
        const unsigned short* ewt = ws + EWT_OFF;
        const int kh = wid >> 2;
        const int ntE = wid & 3;
        const int bc = ntE * 16 + l15;
        const int arow = l15 & 3;
        f32x4 acc = {0.f, 0.f, 0.f, 0.f};
        const int ks0 = kh * 25;
        for (int ks = ks0; ks < ks0 + 25; ++ks) {
            const short8 af = *(const short8*)&featbuf[arow * FB_STRIDE + ks * 32 + lg * 8];
            const short8 bf = *(const short8*)&ewt[(ks * 64 + bc) * 32 + lg * 8];
            acc = __builtin_amdgcn_mfma_f32_16x16x32_bf16(af, bf, acc, 0, 0, 0);
        }
        if (lane < 16 && bc < 56) {
            allC[kh][0 * 56 + bc] = acc.x;
            allC[kh][1 * 56 + bc] = acc.y;
            allC[kh][2 * 56 + bc] = acc.z;
            allC[kh][3 * 56 + bc] = acc.w;
        }
    }
    __syncthreads();

    if (tid < 4) {
        const int img = img0 + tid;
        if (img < B) {
            float gv[5], mx = -1e30f;
            #pragma unroll
            for (int g = 0; g < 5; g++) {
                gv[g] = allC[0][tid * 56 + 50 + g] + allC[1][tid * 56 + 50 + g] + gb[g];
                mx = fmaxf(mx, gv[g]);
            }
            float ssum = 0.f;
            #pragma unroll
            for (int g = 0; g < 5; g++) { gv[g] = expf(gv[g] - mx); ssum += gv[g]; }
            const float inv = 1.f / ssum;
            #pragma unroll
            for (int g = 0; g < 5; g++) gv[g] *= inv;

            int idx0, idx1, idx2; float wv0, wv1, wv2;
            unsigned usedMask = 0;
            {
                int bi = 0; float bv = -1e30f;
                #pragma unroll
                for (int g = 0; g < 5; g++)
                    if (gv[g] > bv) { bv = gv[g]; bi = g; }
                idx0 = bi; wv0 = bv; usedMask |= (1u << bi);
            }
            {
                int bi = 0; float bv = -1e30f;
                #pragma unroll
                for (int g = 0; g < 5; g++)
                    if (!(usedMask & (1u << g)) && gv[g] > bv) { bv = gv[g]; bi = g; }
                idx1 = bi; wv1 = bv; usedMask |= (1u << bi);
            }
            {
                int bi = 0; float bv = -1e30f;
                #pragma unroll
                for (int g = 0; g < 5; g++)
                    if (!(usedMask & (1u << g)) && gv[g] > bv) { bv = gv[g]; bi = g; }
                idx2 = bi; wv2 = bv;
            }
            float comb[10];
            #pragma unroll
            for (int cc = 0; cc < 10; cc++) {
                comb[cc] = wv0 * (allC[0][tid * 56 + idx0 * 10 + cc] + allC[1][tid * 56 + idx0 * 10 + cc] + eb[idx0 * 10 + cc])
                         + wv1 * (allC[0][tid * 56 + idx1 * 10 + cc] + allC[1][tid * 56 + idx1 * 10 + cc] + eb[idx1 * 10 + cc])
                         + wv2 * (allC[0][tid * 56 + idx2 * 10 + cc] + allC[1][tid * 56 + idx2 * 10 + cc] + eb[idx2 * 10 + cc]);
            }
            float m2 = -1e30f;
            #pragma unroll
            for (int cc = 0; cc < 10; cc++) m2 = fmaxf(m2, comb[cc]);
            float e[10], s2 = 0.f;
            #pragma unroll
            for (int cc = 0; cc < 10; cc++) { e[cc] = expf(comb[cc] - m2); s2 += e[cc]; }
            const float inv2 = 1.f / s2;
            #pragma unroll
            for (int cc = 0; cc < 10; cc++) out[(size_t)img * 10 + cc] = e[cc] * inv2;
        }
    }
}

extern "C" void kernel_launch(void* const* d_in, const int* in_sizes, int n_in,
                              void* d_out, int out_size, void* d_ws, size_t ws_size,
                              hipStream_t stream) {
    const float* x   = (const float*)d_in[0];
    const float* w1  = (const float*)d_in[1];
    const float* b1  = (const float*)d_in[2];
    const float* w2  = (const float*)d_in[3];
    const float* b2  = (const float*)d_in[4];
    const float* gw  = (const float*)d_in[5];
    const float* gb  = (const float*)d_in[6];
    const float* ew  = (const float*)d_in[7];
    const float* eb  = (const float*)d_in[8];
    float* out = (float*)d_out;
    const int B = in_sizes[0] / 784;

    unsigned short* ws = (unsigned short*)d_ws;
    const size_t ws_full = ((size_t)WS_SHORTS + (size_t)B * 1600) * sizeof(unsigned short);

    moe_prep<<<(WS_SHORTS + 255) / 256, 256, 0, stream>>>(w2, gw, ew, w1, ws);
    if (ws_size >= ws_full) {
        moe_conv<<<(B + IPB - 1) / IPB, BLOCK, 0, stream>>>(x, b1, b2, ws, ws + FEAT_OFF, B);
        moe_expert<<<(B + EIPB - 1) / EIPB, BLOCK, 0, stream>>>(ws, gb, eb, out, B);
    } else {
        moe_main_fused<<<(B + 3) / 4, BLOCK, 0, stream>>>(x, b1, b2, gb, eb, ws, out, B);
    }
}

// Round 18
// 80.209 us; speedup vs baseline: 3.1995x; 3.1995x over previous
//
#include <hip/hip_runtime.h>
#include <hip/hip_bf16.h>

#define BLOCK 512
#define IPB 8            // images per block (conv kernel)
#define EIPB 16          // images per block (expert kernel)
#define FB_STRIDE 1616   // fused-path featbuf stride (shorts)
#define ES_STRIDE 1608   // expert featS stride: 804 dw = 4 mod 32 -> 16-row reads ~2-way
#define H1_STRIDE 40     // h1p row stride in shorts: 80 B, 16B-aligned

// ws layout (shorts):
#define W2T_OFF 0        // [kpos=9][oc=64][j=32]  (j = ic-pair-interleaved)   18432
#define EWT_OFF 18432    // [ks=50][n=64][k=32] experts+gate (k perm'd)        102400
#define W1C_OFF 120832   // [n=32][k=32] conv1 B: k0-8 w1hi, k16-24 w1lo, rest 0
#define WS_SHORTS 121856
#define FEAT_OFF 121856  // [B][1600] bf16 feat (k perm'd) — full path only

typedef __attribute__((ext_vector_type(8))) short short8;
typedef __attribute__((ext_vector_type(4))) float f32x4;

#define SEL_LO 0x05040100u   // perm(y,x,SEL_LO) = (x&0xffff)|(y<<16) : low halves

static __device__ __forceinline__ unsigned short f2bf(float f) {
    unsigned int u = __builtin_bit_cast(unsigned int, f);
    u = (u + 0x7FFFu + ((u >> 16) & 1u)) >> 16;   // RNE
    return (unsigned short)u;
}
static __device__ __forceinline__ float bf2f(unsigned short h) {
    unsigned int u = ((unsigned int)h) << 16;
    return __builtin_bit_cast(float, u);
}
// single-instruction RNE pack: low16 = bf16(a), high16 = bf16(b)
static __device__ __forceinline__ unsigned int cvtpk(float a, float b) {
    unsigned int r;
    asm("v_cvt_pk_bf16_f32 %0, %1, %2" : "=v"(r) : "v"(a), "v"(b));
    return r;
}

// ---------------- prep kernel: build bf16 weight layouts in d_ws ----------------
__global__ void moe_prep(const float* __restrict__ w2, const float* __restrict__ gw,
                         const float* __restrict__ ew, const float* __restrict__ w1,
                         unsigned short* __restrict__ ws) {
    int i = blockIdx.x * 256 + threadIdx.x;
    if (i < 18432) {
        int kpos = i >> 11, rem = i & 2047, oc = rem >> 5, j = rem & 31;
        int ic = ((j & 1) << 4) | (j >> 1);        // h1p pair-interleave: j=2*l+h <-> ic=h*16+l
        ws[W2T_OFF + i] = f2bf(w2[(kpos * 32 + ic) * 64 + oc]);
    }
    int j2 = i - EWT_OFF;
    if (j2 >= 0 && j2 < 102400) {
        int ks = j2 >> 11, rem = j2 & 2047, n = rem >> 5, k = rem & 31;
        int kk = ks * 32 + k;                      // permuted flatten index
        int wv = kk >> 6, jj = kk & 63;
        int r = jj & 31;
        int oc = ((jj >> 5) << 5) | ((r & 1) << 4) | (r >> 1);   // feat pair-interleave
        int d = wv * 64 + oc;                      // original flatten dim
        float v = 0.f;
        if (n < 50)      v = ew[(n / 10) * 16000 + d * 10 + (n % 10)];
        else if (n < 55) v = gw[d * 5 + (n - 50)];
        ws[EWT_OFF + j2] = f2bf(v);
    }
    int p = i - W1C_OFF;
    if (p >= 0 && p < 1024) {
        // conv1 B, two-pattern layout: k0-8 = w1hi(tap k), k16-24 = w1lo(tap k-16), rest 0
        int n = p >> 5, k = p & 31;
        unsigned short val = 0;
        if (k < 9) {
            val = f2bf(w1[k * 32 + n]);
        } else if (k >= 16 && k < 25) {
            float w = w1[(k - 16) * 32 + n];
            unsigned short hi = f2bf(w);
            val = f2bf(w - bf2f(hi));
        }
        ws[W1C_OFF + p] = val;
    }
}

// ---------------- conv kernel: conv1+pool -> conv2+pool -> feat (global) ----------------
// NOTE: this toolchain treats __launch_bounds__ arg2 as min BLOCKS/CU (CUDA semantics).
// N=3 -> 85-VGPR cap; HW occupancy halves past 64 VGPR — compiler lands at exactly 64.
// Measured dead ends from this point: acc-split (+8 VGPR -> occupancy halves, r15);
// 1x4 N-tiles (16 accs + 4 global bfrag streams -> spills under 64-cap, r17).
__global__ __launch_bounds__(BLOCK, 3)
void moe_conv(const float* __restrict__ x, const float* __restrict__ b1,
              const float* __restrict__ b2, const unsigned short* __restrict__ ws,
              unsigned short* __restrict__ feat, int B)
{
    __shared__ unsigned int xsp[2][784];                        // bf16(x) dup-packed, 6272 B
    __shared__ __align__(16) unsigned short h1p[2][169 * H1_STRIDE];   // 27040 B

    const int tid  = threadIdx.x;
    const int wid  = tid >> 6;
    const int lane = tid & 63;
    const int l15  = lane & 15;
    const int lg   = lane >> 4;

    // conv2: wave owns M-tiles {mt0, mt0+4} x N-tiles {n0, n0+1}
    const int mt0 = wid >> 1;
    const int n0  = (wid & 1) * 2;
    short8 bfA[9], bfB[9];
    #pragma unroll
    for (int kp = 0; kp < 9; kp++) {
        bfA[kp] = *(const short8*)&ws[W2T_OFF + (kp * 64 + n0 * 16 + l15) * 32 + lg * 8];
        bfB[kp] = *(const short8*)&ws[W2T_OFF + (kp * 64 + (n0 + 1) * 16 + l15) * 32 + lg * 8];
    }
    const short8 c1f0 = *(const short8*)&ws[W1C_OFF + l15 * 32 + lg * 8];
    const short8 c1f1 = *(const short8*)&ws[W1C_OFF + (16 + l15) * 32 + lg * 8];

    // per-lane bias constants (L1/L2 hits; replaces per-iter LDS reads)
    const float bias1a = b1[l15];
    const float bias1b = b1[16 + l15];
    const float bias2a = b2[n0 * 16 + l15];
    const float bias2b = b2[n0 * 16 + l15 + 16];

    // ---- image-invariant conv1 addressing (hoisted out of image loop) ----
    int xoff1[6], hoff1[6];
    bool val1[6];
    #pragma unroll
    for (int j = 0; j < 6; ++j) {
        const int mt = wid + 8 * j;
        int wsrc = mt * 4 + (l15 >> 2); if (wsrc > 168) wsrc = 168;
        const int s = l15 & 3;
        const int cy = 2 * (wsrc / 13) + (s >> 1);
        const int cx = 2 * (wsrc % 13) + (s & 1);
        xoff1[j] = cy * 28 + cx;
        const int window = mt * 4 + lg;
        val1[j] = (mt < 43) && (window < 169);
        hoff1[j] = (window < 169 ? window : 0) * H1_STRIDE + 2 * l15;
    }
    // ---- image-invariant conv2 addressing ----
    int aoff2[2], foff2[2];
    bool val2[2];
    #pragma unroll
    for (int mi = 0; mi < 2; ++mi) {
        const int mt = mt0 + mi * 4;
        const int m = mt * 16 + l15;
        int wsrc = m >> 2; if (wsrc > 24) wsrc = 24;
        const int s = m & 3;
        const int cy = 2 * (wsrc / 5) + (s >> 1);
        const int cx = 2 * (wsrc % 5) + (s & 1);
        aoff2[mi] = (cy * 13 + cx) * (H1_STRIDE * 2) + lg * 16;   // byte offset into h1p
        const int wv = mt * 4 + lg;
        val2[mi] = (wv < 25);
        foff2[mi] = (wv < 25 ? wv : 0) * 64 + ((n0 >> 1) << 5) + 2 * l15;
    }

    const int img0 = blockIdx.x * IPB;
    {   // prologue: stage image 0 (bf16 dup-packed, 1 cvt_pk per element)
        int im = img0 < B ? img0 : B - 1;
        const float* xg = x + (size_t)im * 784;
        xsp[0][tid] = cvtpk(xg[tid], xg[tid]);
        if (tid + BLOCK < 784) xsp[0][tid + BLOCK] = cvtpk(xg[tid + BLOCK], xg[tid + BLOCK]);
    }
    __syncthreads();

    // software-pipelined phases: phase p = conv2(img p-1) || conv1(img p)
    #pragma unroll
    for (int p = 0; p <= IPB; ++p) {
        const bool do_c1 = (p < IPB);
        const bool do_c2 = (p >= 1);
        const bool pre   = (p + 1 < IPB);

        float f0 = 0.f, f1 = 0.f;
        if (pre) {
            int im2 = img0 + p + 1; if (im2 >= B) im2 = B - 1;
            const float* xg2 = x + (size_t)im2 * 784;
            f0 = xg2[tid];
            if (tid + BLOCK < 784) f1 = xg2[tid + BLOCK];
        }

        // conv2(img p-1): implicit-GEMM MFMA (single-chain accs), h1p -> global feat
        if (do_c2) {
            const int it = p - 1;
            const int img = img0 + it;
            const unsigned short* h1cur = h1p[it & 1];
            unsigned short* frow = feat + (size_t)img * 1600;
            #pragma unroll
            for (int mi = 0; mi < 2; ++mi) {
                const char* abase = (const char*)h1cur + aoff2[mi];
                f32x4 a0 = {0.f, 0.f, 0.f, 0.f};
                f32x4 a1 = {0.f, 0.f, 0.f, 0.f};
                #pragma unroll
                for (int kp = 0; kp < 9; kp++) {
                    const int ky = kp / 3, kx = kp % 3;
                    const short8 af = *(const short8*)(abase + (ky * 13 + kx) * (H1_STRIDE * 2));
                    a0 = __builtin_amdgcn_mfma_f32_16x16x32_bf16(af, bfA[kp], a0, 0, 0, 0);
                    a1 = __builtin_amdgcn_mfma_f32_16x16x32_bf16(af, bfB[kp], a1, 0, 0, 0);
                }
                if (val2[mi] && img < B) {
                    const float m0 = fmaxf(fmaxf(a0.x, a0.y), fmaxf(a0.z, a0.w)) + bias2a;
                    const float m1 = fmaxf(fmaxf(a1.x, a1.y), fmaxf(a1.z, a1.w)) + bias2b;
                    *(unsigned int*)&frow[foff2[mi]] = cvtpk(fmaxf(m0, 0.f), fmaxf(m1, 0.f));
                }
            }
        }

        // conv1(img p): branch-sunk tap loads (even lanes 8 reads, odd lanes 1) -> MFMA -> h1p
        if (do_c1) {
            const unsigned int* xcur = xsp[p & 1];
            unsigned short* h1dst = h1p[p & 1];
            #pragma unroll
            for (int j = 0; j < 6; ++j) {
                if (wid + 8 * j < 43) {
                    const unsigned int* xb = xcur + xoff1[j];
                    unsigned int a0 = 0u, a1 = 0u, a2 = 0u, a3 = 0u;
                    if ((lg & 1) == 0) {
                        const unsigned int t0 = xb[0],  t1 = xb[1],  t2 = xb[2];
                        const unsigned int t3 = xb[28], t4 = xb[29], t5 = xb[30];
                        const unsigned int t6 = xb[56], t7 = xb[57];
                        a0 = __builtin_amdgcn_perm(t1, t0, SEL_LO);
                        a1 = __builtin_amdgcn_perm(t3, t2, SEL_LO);
                        a2 = __builtin_amdgcn_perm(t5, t4, SEL_LO);
                        a3 = __builtin_amdgcn_perm(t7, t6, SEL_LO);
                    } else {
                        a0 = xb[58] & 0xffffu;
                    }
                    const uint4 av = make_uint4(a0, a1, a2, a3);
                    const short8 af = __builtin_bit_cast(short8, av);
                    f32x4 p0 = {0.f, 0.f, 0.f, 0.f};
                    f32x4 p1 = {0.f, 0.f, 0.f, 0.f};
                    p0 = __builtin_amdgcn_mfma_f32_16x16x32_bf16(af, c1f0, p0, 0, 0, 0);
                    p1 = __builtin_amdgcn_mfma_f32_16x16x32_bf16(af, c1f1, p1, 0, 0, 0);
                    if (val1[j]) {
                        const float m0 = fmaxf(fmaxf(p0.x, p0.y), fmaxf(p0.z, p0.w)) + bias1a;
                        const float m1 = fmaxf(fmaxf(p1.x, p1.y), fmaxf(p1.z, p1.w)) + bias1b;
                        *(unsigned int*)&h1dst[hoff1[j]] = cvtpk(fmaxf(m0, 0.f), fmaxf(m1, 0.f));
                    }
                }
            }
        }

        if (pre) {
            xsp[(p + 1) & 1][tid] = cvtpk(f0, f0);
            if (tid + BLOCK < 784) xsp[(p + 1) & 1][tid + BLOCK] = cvtpk(f1, f1);
        }
        __syncthreads();
    } // p
}

// ---------------- expert kernel: [B x 1600] @ [1600 x 55] + gate/top3/softmax ----------------
// (LDS-staged featS — coalesced global reads, conflict-free MFMA reads)
__global__ __launch_bounds__(BLOCK, 2)
void moe_expert(const unsigned short* __restrict__ ws, const float* __restrict__ gb,
                const float* __restrict__ eb, float* __restrict__ out, int B)
{
    __shared__ __align__(16) unsigned short featS[EIPB * ES_STRIDE];   // 51456 B
    __shared__ float allC[2][EIPB][64];                                 // 8192 B

    const int tid  = threadIdx.x;
    const int wid  = tid >> 6;
    const int lane = tid & 63;
    const int l15  = lane & 15;
    const int lg   = lane >> 4;

    const unsigned short* feat = ws + FEAT_OFF;
    const unsigned short* ewt  = ws + EWT_OFF;
    const int img0 = blockIdx.x * EIPB;

    for (int i = tid; i < EIPB * 800; i += BLOCK) {
        const int r = i / 800, c = i - r * 800;
        const int img = img0 + r;
        unsigned int v = 0u;
        if (img < B) v = *(const unsigned int*)&feat[(size_t)img * 1600 + 2 * c];
        *(unsigned int*)&featS[r * ES_STRIDE + 2 * c] = v;
    }
    __syncthreads();

    {
        const int kh  = wid >> 2;
        const int ntE = wid & 3;
        const int bc  = ntE * 16 + l15;
        f32x4 acc = {0.f, 0.f, 0.f, 0.f};
        const int ks0 = kh * 25;
        for (int ks = ks0; ks < ks0 + 25; ++ks) {
            const short8 af = *(const short8*)&featS[l15 * ES_STRIDE + ks * 32 + lg * 8];
            const short8 bf = *(const short8*)&ewt[(ks * 64 + bc) * 32 + lg * 8];
            acc = __builtin_amdgcn_mfma_f32_16x16x32_bf16(af, bf, acc, 0, 0, 0);
        }
        const int r0 = lg * 4;
        allC[kh][r0 + 0][bc] = acc.x;
        allC[kh][r0 + 1][bc] = acc.y;
        allC[kh][r0 + 2][bc] = acc.z;
        allC[kh][r0 + 3][bc] = acc.w;
    }
    __syncthreads();

    if (tid < EIPB) {
        const int img = img0 + tid;
        if (img < B) {
            float gv[5], mx = -1e30f;
            #pragma unroll
            for (int g = 0; g < 5; g++) {
                gv[g] = allC[0][tid][50 + g] + allC[1][tid][50 + g] + gb[g];
                mx = fmaxf(mx, gv[g]);
            }
            float ssum = 0.f;
            #pragma unroll
            for (int g = 0; g < 5; g++) { gv[g] = expf(gv[g] - mx); ssum += gv[g]; }
            const float inv = 1.f / ssum;
            #pragma unroll
            for (int g = 0; g < 5; g++) gv[g] *= inv;

            int idx0, idx1, idx2; float wv0, wv1, wv2;
            unsigned usedMask = 0;
            {
                int bi = 0; float bv = -1e30f;
                #pragma unroll
                for (int g = 0; g < 5; g++)
                    if (gv[g] > bv) { bv = gv[g]; bi = g; }   // strict >: lowest idx on tie
                idx0 = bi; wv0 = bv; usedMask |= (1u << bi);
            }
            {
                int bi = 0; float bv = -1e30f;
                #pragma unroll
                for (int g = 0; g < 5; g++)
                    if (!(usedMask & (1u << g)) && gv[g] > bv) { bv = gv[g]; bi = g; }
                idx1 = bi; wv1 = bv; usedMask |= (1u << bi);
            }
            {
                int bi = 0; float bv = -1e30f;
                #pragma unroll
                for (int g = 0; g < 5; g++)
                    if (!(usedMask & (1u << g)) && gv[g] > bv) { bv = gv[g]; bi = g; }
                idx2 = bi; wv2 = bv;
            }
            float comb[10];
            #pragma unroll
            for (int cc = 0; cc < 10; cc++) {
                comb[cc] = wv0 * (allC[0][tid][idx0 * 10 + cc] + allC[1][tid][idx0 * 10 + cc] + eb[idx0 * 10 + cc])
                         + wv1 * (allC[0][tid][idx1 * 10 + cc] + allC[1][tid][idx1 * 10 + cc] + eb[idx1 * 10 + cc])
                         + wv2 * (allC[0][tid][idx2 * 10 + cc] + allC[1][tid][idx2 * 10 + cc] + eb[idx2 * 10 + cc]);
            }
            float m2 = -1e30f;
            #pragma unroll
            for (int cc = 0; cc < 10; cc++) m2 = fmaxf(m2, comb[cc]);
            float e[10], s2 = 0.f;
            #pragma unroll
            for (int cc = 0; cc < 10; cc++) { e[cc] = expf(comb[cc] - m2); s2 += e[cc]; }
            const float inv2 = 1.f / s2;
            #pragma unroll
            for (int cc = 0; cc < 10; cc++) out[(size_t)img * 10 + cc] = e[cc] * inv2;
        }
    }
}

// ---------------- fused fallback (used when ws can't hold feat) ----------------
__global__ __launch_bounds__(BLOCK, 3)
void moe_main_fused(const float* __restrict__ x, const float* __restrict__ b1,
                    const float* __restrict__ b2, const float* __restrict__ gb,
                    const float* __restrict__ eb, const unsigned short* __restrict__ ws,
                    float* __restrict__ out, int B)
{
    __shared__ unsigned int xsp[2][784];
    __shared__ __align__(16) unsigned short h1p[2][169 * H1_STRIDE];
    __shared__ __align__(16) unsigned short featbuf[4 * FB_STRIDE];
    __shared__ float allC[2][4 * 56];

    const int tid  = threadIdx.x;
    const int wid  = tid >> 6;
    const int lane = tid & 63;
    const int l15  = lane & 15;
    const int lg   = lane >> 4;

    const int mt0 = wid >> 1;
    const int n0  = (wid & 1) * 2;
    short8 bfA[9], bfB[9];
    #pragma unroll
    for (int kp = 0; kp < 9; kp++) {
        bfA[kp] = *(const short8*)&ws[W2T_OFF + (kp * 64 + n0 * 16 + l15) * 32 + lg * 8];
        bfB[kp] = *(const short8*)&ws[W2T_OFF + (kp * 64 + (n0 + 1) * 16 + l15) * 32 + lg * 8];
    }
    const short8 c1f0 = *(const short8*)&ws[W1C_OFF + l15 * 32 + lg * 8];
    const short8 c1f1 = *(const short8*)&ws[W1C_OFF + (16 + l15) * 32 + lg * 8];

    const float bias1a = b1[l15];
    const float bias1b = b1[16 + l15];
    const float bias2a = b2[n0 * 16 + l15];
    const float bias2b = b2[n0 * 16 + l15 + 16];

    const int img0 = blockIdx.x * 4;
    {
        int im = img0 < B ? img0 : B - 1;
        const float* xg = x + (size_t)im * 784;
        xsp[0][tid] = cvtpk(xg[tid], xg[tid]);
        if (tid + BLOCK < 784) xsp[0][tid + BLOCK] = cvtpk(xg[tid + BLOCK], xg[tid + BLOCK]);
    }
    __syncthreads();

    #pragma unroll
    for (int p = 0; p <= 4; ++p) {
        const bool do_c1 = (p < 4);
        const bool do_c2 = (p >= 1);
        const bool pre   = (p + 1 < 4);

        float f0 = 0.f, f1 = 0.f;
        if (pre) {
            int im2 = img0 + p + 1; if (im2 >= B) im2 = B - 1;
            const float* xg2 = x + (size_t)im2 * 784;
            f0 = xg2[tid];
            if (tid + BLOCK < 784) f1 = xg2[tid + BLOCK];
        }

        if (do_c2) {
            const int it = p - 1;
            const unsigned short* h1cur = h1p[it & 1];
            #pragma unroll
            for (int mi = 0; mi < 2; ++mi) {
                const int mt = mt0 + mi * 4;
                const int m = mt * 16 + l15;
                int wsrc = m >> 2; if (wsrc > 24) wsrc = 24;
                const int s = m & 3;
                const int cy = 2 * (wsrc / 5) + (s >> 1);
                const int cx = 2 * (wsrc % 5) + (s & 1);
                const char* abase = (const char*)h1cur + (cy * 13 + cx) * (H1_STRIDE * 2) + lg * 16;
                f32x4 a0 = {0.f, 0.f, 0.f, 0.f};
                f32x4 a1 = {0.f, 0.f, 0.f, 0.f};
                #pragma unroll
                for (int kp = 0; kp < 9; kp++) {
                    const int ky = kp / 3, kx = kp % 3;
                    const short8 af = *(const short8*)(abase + (ky * 13 + kx) * (H1_STRIDE * 2));
                    a0 = __builtin_amdgcn_mfma_f32_16x16x32_bf16(af, bfA[kp], a0, 0, 0, 0);
                    a1 = __builtin_amdgcn_mfma_f32_16x16x32_bf16(af, bfB[kp], a1, 0, 0, 0);
                }
                const int wv = mt * 4 + lg;
                if (wv < 25) {
                    const float m0 = fmaxf(fmaxf(a0.x, a0.y), fmaxf(a0.z, a0.w)) + bias2a;
                    const float m1 = fmaxf(fmaxf(a1.x, a1.y), fmaxf(a1.z, a1.w)) + bias2b;
                    *(unsigned int*)&featbuf[it * FB_STRIDE + wv * 64 + ((n0 >> 1) << 5) + 2 * l15] =
                        cvtpk(fmaxf(m0, 0.f), fmaxf(m1, 0.f));
                }
            }
        }

        if (do_c1) {
            const unsigned int* xcur = xsp[p & 1];
            unsigned short* h1dst = h1p[p & 1];
            for (int mt = wid; mt < 43; mt += 8) {
                int wsrc = mt * 4 + (l15 >> 2); if (wsrc > 168) wsrc = 168;
                const int s  = l15 & 3;
                const int cy = 2 * (wsrc / 13) + (s >> 1);
                const int cx = 2 * (wsrc % 13) + (s & 1);
                const unsigned int* xb = &xcur[cy * 28 + cx];
                unsigned int a0 = 0u, a1 = 0u, a2 = 0u, a3 = 0u;
                if ((lg & 1) == 0) {
                    const unsigned int t0 = xb[0],  t1 = xb[1],  t2 = xb[2];
                    const unsigned int t3 = xb[28], t4 = xb[29], t5 = xb[30];
                    const unsigned int t6 = xb[56], t7 = xb[57];
                    a0 = __builtin_amdgcn_perm(t1, t0, SEL_LO);
                    a1 = __builtin_amdgcn_perm(t3, t2, SEL_LO);
                    a2 = __builtin_amdgcn_perm(t5, t4, SEL_LO);
                    a3 = __builtin_amdgcn_perm(t7, t6, SEL_LO);
                } else {
                    a0 = xb[58] & 0xffffu;
                }
                const uint4 av = make_uint4(a0, a1, a2, a3);
                const short8 af = __builtin_bit_cast(short8, av);
                f32x4 p0 = {0.f, 0.f, 0.f, 0.f};
                f32x4 p1 = {0.f, 0.f, 0.f, 0.f};
                p0 = __builtin_amdgcn_mfma_f32_16x16x32_bf16(af, c1f0, p0, 0, 0, 0);
                p1 = __builtin_amdgcn_mfma_f32_16x16x32_bf16(af, c1f1, p1, 0, 0, 0);
                const int window = mt * 4 + lg;
                if (window < 169) {
                    const float m0 = fmaxf(fmaxf(p0.x, p0.y), fmaxf(p0.z, p0.w)) + bias1a;
                    const float m1 = fmaxf(fmaxf(p1.x, p1.y), fmaxf(p1.z, p1.w)) + bias1b;
                    *(unsigned int*)&h1dst[window * H1_STRIDE + 2 * l15] =
                        cvtpk(fmaxf(m0, 0.f), fmaxf(m1, 0.f));
                }
            }
        }

        if (pre) {
            xsp[(p + 1) & 1][tid] = cvtpk(f0, f0);
            if (tid + BLOCK < 784) xsp[(p + 1) & 1][tid + BLOCK] = cvtpk(f1, f1);
        }
        __syncthreads();
    } // p

    {
        const unsigned short* ewt = ws + EWT_OFF;
        const int kh = wid >> 2;
        const int ntE = wid & 3;
        const int bc = ntE * 16 + l15;
        const int arow = l15 & 3;
        f32x4 acc = {0.f, 0.f, 0.f, 0.f};
        const int ks0 = kh * 25;
        for (int ks = ks0; ks < ks0 + 25; ++ks) {
            const short8 af = *(const short8*)&featbuf[arow * FB_STRIDE + ks * 32 + lg * 8];
            const short8 bf = *(const short8*)&ewt[(ks * 64 + bc) * 32 + lg * 8];
            acc = __builtin_amdgcn_mfma_f32_16x16x32_bf16(af, bf, acc, 0, 0, 0);
        }
        if (lane < 16 && bc < 56) {
            allC[kh][0 * 56 + bc] = acc.x;
            allC[kh][1 * 56 + bc] = acc.y;
            allC[kh][2 * 56 + bc] = acc.z;
            allC[kh][3 * 56 + bc] = acc.w;
        }
    }
    __syncthreads();

    if (tid < 4) {
        const int img = img0 + tid;
        if (img < B) {
            float gv[5], mx = -1e30f;
            #pragma unroll
            for (int g = 0; g < 5; g++) {
                gv[g] = allC[0][tid * 56 + 50 + g] + allC[1][tid * 56 + 50 + g] + gb[g];
                mx = fmaxf(mx, gv[g]);
            }
            float ssum = 0.f;
            #pragma unroll
            for (int g = 0; g < 5; g++) { gv[g] = expf(gv[g] - mx); ssum += gv[g]; }
            const float inv = 1.f / ssum;
            #pragma unroll
            for (int g = 0; g < 5; g++) gv[g] *= inv;

            int idx0, idx1, idx2; float wv0, wv1, wv2;
            unsigned usedMask = 0;
            {
                int bi = 0; float bv = -1e30f;
                #pragma unroll
                for (int g = 0; g < 5; g++)
                    if (gv[g] > bv) { bv = gv[g]; bi = g; }
                idx0 = bi; wv0 = bv; usedMask |= (1u << bi);
            }
            {
                int bi = 0; float bv = -1e30f;
                #pragma unroll
                for (int g = 0; g < 5; g++)
                    if (!(usedMask & (1u << g)) && gv[g] > bv) { bv = gv[g]; bi = g; }
                idx1 = bi; wv1 = bv; usedMask |= (1u << bi);
            }
            {
                int bi = 0; float bv = -1e30f;
                #pragma unroll
                for (int g = 0; g < 5; g++)
                    if (!(usedMask & (1u << g)) && gv[g] > bv) { bv = gv[g]; bi = g; }
                idx2 = bi; wv2 = bv;
            }
            float comb[10];
            #pragma unroll
            for (int cc = 0; cc < 10; cc++) {
                comb[cc] = wv0 * (allC[0][tid * 56 + idx0 * 10 + cc] + allC[1][tid * 56 + idx0 * 10 + cc] + eb[idx0 * 10 + cc])
                         + wv1 * (allC[0][tid * 56 + idx1 * 10 + cc] + allC[1][tid * 56 + idx1 * 10 + cc] + eb[idx1 * 10 + cc])
                         + wv2 * (allC[0][tid * 56 + idx2 * 10 + cc] + allC[1][tid * 56 + idx2 * 10 + cc] + eb[idx2 * 10 + cc]);
            }
            float m2 = -1e30f;
            #pragma unroll
            for (int cc = 0; cc < 10; cc++) m2 = fmaxf(m2, comb[cc]);
            float e[10], s2 = 0.f;
            #pragma unroll
            for (int cc = 0; cc < 10; cc++) { e[cc] = expf(comb[cc] - m2); s2 += e[cc]; }
            const float inv2 = 1.f / s2;
            #pragma unroll
            for (int cc = 0; cc < 10; cc++) out[(size_t)img * 10 + cc] = e[cc] * inv2;
        }
    }
}

extern "C" void kernel_launch(void* const* d_in, const int* in_sizes, int n_in,
                              void* d_out, int out_size, void* d_ws, size_t ws_size,
                              hipStream_t stream) {
    const float* x   = (const float*)d_in[0];
    const float* w1  = (const float*)d_in[1];
    const float* b1  = (const float*)d_in[2];
    const float* w2  = (const float*)d_in[3];
    const float* b2  = (const float*)d_in[4];
    const float* gw  = (const float*)d_in[5];
    const float* gb  = (const float*)d_in[6];
    const float* ew  = (const float*)d_in[7];
    const float* eb  = (const float*)d_in[8];
    float* out = (float*)d_out;
    const int B = in_sizes[0] / 784;

    unsigned short* ws = (unsigned short*)d_ws;
    const size_t ws_full = ((size_t)WS_SHORTS + (size_t)B * 1600) * sizeof(unsigned short);

    moe_prep<<<(WS_SHORTS + 255) / 256, 256, 0, stream>>>(w2, gw, ew, w1, ws);
    if (ws_size >= ws_full) {
        moe_conv<<<(B + IPB - 1) / IPB, BLOCK, 0, stream>>>(x, b1, b2, ws, ws + FEAT_OFF, B);
        moe_expert<<<(B + EIPB - 1) / EIPB, BLOCK, 0, stream>>>(ws, gb, eb, out, B);
    } else {
        moe_main_fused<<<(B + 3) / 4, BLOCK, 0, stream>>>(x, b1, b2, gb, eb, ws, out, B);
    }
}